// Round 1
// baseline (179.653 us; speedup 1.0000x reference)
//
#include <hip/hip_runtime.h>

// Problem constants (from reference setup_inputs): B=16, C=64, H=W=256.
#define NB 16
#define NC 64
#define HW 65536            // 256*256
#define BN_EPS 1e-5f

// ---------------------------------------------------------------------------
// Kernel 1: per-(b,c) masked reduction over HW.
// One block of 256 threads per (b,c). Each thread: 64 float4 loads of x and
// the (broadcast-over-c) mask, predicated accumulate of {sum, sumsq, cnt}.
// ---------------------------------------------------------------------------
__global__ __launch_bounds__(256) void mbn_stats(const float* __restrict__ x,
                                                 const float* __restrict__ mask,
                                                 float* __restrict__ ws) {
    const int bc = blockIdx.x;          // 0..1023
    const int b  = bc >> 6;             // /NC
    const float* xp = x + (size_t)bc * HW;
    const float* mp = mask + (size_t)b * HW;

    float s = 0.f, ss = 0.f, cn = 0.f;
    for (int i = threadIdx.x * 4; i < HW; i += 256 * 4) {
        float4 xv = *reinterpret_cast<const float4*>(xp + i);
        float4 mv = *reinterpret_cast<const float4*>(mp + i);
        float v0 = mv.x > 0.5f ? 1.f : 0.f;
        float v1 = mv.y > 0.5f ? 1.f : 0.f;
        float v2 = mv.z > 0.5f ? 1.f : 0.f;
        float v3 = mv.w > 0.5f ? 1.f : 0.f;
        s  += xv.x * v0 + xv.y * v1 + xv.z * v2 + xv.w * v3;
        ss += xv.x * xv.x * v0 + xv.y * xv.y * v1
            + xv.z * xv.z * v2 + xv.w * xv.w * v3;
        cn += v0 + v1 + v2 + v3;
    }

    // wave-64 butterfly, then cross-wave via LDS (4 waves)
    for (int off = 32; off > 0; off >>= 1) {
        s  += __shfl_down(s,  off);
        ss += __shfl_down(ss, off);
        cn += __shfl_down(cn, off);
    }
    __shared__ float red[3][4];
    const int wave = threadIdx.x >> 6;
    const int lane = threadIdx.x & 63;
    if (lane == 0) { red[0][wave] = s; red[1][wave] = ss; red[2][wave] = cn; }
    __syncthreads();
    if (threadIdx.x == 0) {
        s  = red[0][0] + red[0][1] + red[0][2] + red[0][3];
        ss = red[1][0] + red[1][1] + red[1][2] + red[1][3];
        cn = red[2][0] + red[2][1] + red[2][2] + red[2][3];
        ws[bc]        = s;
        ws[1024 + bc] = ss;
        ws[2048 + bc] = cn;
    }
}

// ---------------------------------------------------------------------------
// Kernel 2: fold (B,C) stats -> per-channel scale/shift.
// Reproduces reference edge semantics: mean=0 if cnt==0, var=1 if cnt<=1.
// ---------------------------------------------------------------------------
__global__ __launch_bounds__(64) void mbn_finalize(const float* __restrict__ ws_in,
                                                   const float* __restrict__ weight,
                                                   const float* __restrict__ bias,
                                                   float* __restrict__ sc_sh) {
    const int c = threadIdx.x;          // 0..63
    float fm = 0.f, fv = 0.f;
    for (int b = 0; b < NB; ++b) {
        const int bc = b * NC + c;
        const float s  = ws_in[bc];
        const float ss = ws_in[1024 + bc];
        const float cn = ws_in[2048 + bc];
        const float safe = fmaxf(cn, 1.f);
        const float mean = (cn > 0.f) ? (s / safe) : 0.f;
        const float sq   = ss - 2.f * mean * s + mean * mean * cn;
        const float var  = (cn > 1.f) ? (sq / safe) : 1.f;
        fm += mean;
        fv += var;
    }
    fm *= (1.f / NB);
    fv *= (1.f / NB);
    const float inv   = 1.f / sqrtf(fv + BN_EPS);
    const float scale = weight[c] * inv;
    const float shift = bias[c] - fm * scale;
    sc_sh[c]      = scale;
    sc_sh[64 + c] = shift;
}

// ---------------------------------------------------------------------------
// Kernel 3: elementwise apply: out = valid ? x*scale[c]+shift[c] : x
// float4 grid-stride; 4 consecutive elements share (b,c).
// ---------------------------------------------------------------------------
__global__ __launch_bounds__(256) void mbn_apply(const float* __restrict__ x,
                                                 const float* __restrict__ mask,
                                                 const float* __restrict__ sc_sh,
                                                 float* __restrict__ out) {
    const size_t total4 = (size_t)NB * NC * HW / 4;   // 4,194,304
    const size_t stride = (size_t)gridDim.x * blockDim.x;
    for (size_t i = (size_t)blockIdx.x * blockDim.x + threadIdx.x;
         i < total4; i += stride) {
        const size_t e  = i * 4;
        const int    c  = (int)((e >> 16) & 63);
        const size_t b  = e >> 22;
        const size_t hw = e & 65535;
        float4 xv = *reinterpret_cast<const float4*>(x + e);
        float4 mv = *reinterpret_cast<const float4*>(mask + b * HW + hw);
        const float sc = sc_sh[c];
        const float sh = sc_sh[64 + c];
        float4 o;
        o.x = mv.x > 0.5f ? fmaf(xv.x, sc, sh) : xv.x;
        o.y = mv.y > 0.5f ? fmaf(xv.y, sc, sh) : xv.y;
        o.z = mv.z > 0.5f ? fmaf(xv.z, sc, sh) : xv.z;
        o.w = mv.w > 0.5f ? fmaf(xv.w, sc, sh) : xv.w;
        *reinterpret_cast<float4*>(out + e) = o;
    }
}

extern "C" void kernel_launch(void* const* d_in, const int* in_sizes, int n_in,
                              void* d_out, int out_size, void* d_ws, size_t ws_size,
                              hipStream_t stream) {
    const float* x      = (const float*)d_in[0];
    const float* mask   = (const float*)d_in[1];
    const float* weight = (const float*)d_in[2];
    const float* bias   = (const float*)d_in[3];
    float* out   = (float*)d_out;
    float* ws    = (float*)d_ws;      // [0,1024)=sum [1024,2048)=sumsq [2048,3072)=cnt
    float* sc_sh = ws + 3072;         // [0,64)=scale [64,128)=shift

    mbn_stats<<<NB * NC, 256, 0, stream>>>(x, mask, ws);
    mbn_finalize<<<1, 64, 0, stream>>>(ws, weight, bias, sc_sh);
    mbn_apply<<<2048, 256, 0, stream>>>(x, mask, sc_sh, out);
}

// Round 2
// 143.097 us; speedup vs baseline: 1.2555x; 1.2555x over previous
//
#include <hip/hip_runtime.h>

// Problem constants (from reference setup_inputs): B=16, C=64, H=W=256.
#define NB 16
#define NC 64
#define HW 65536            // 256*256
#define HHW 32768           // HW/2
#define BN_EPS 1e-5f

typedef float f4 __attribute__((ext_vector_type(4)));

// ---------------------------------------------------------------------------
// Kernel 1: per-(b,c,half) masked reduction. 2048 blocks x 256 threads.
// Each block reduces half a (b,c) plane: 32 float4 loads/thread.
// ws layout: psum[2048] | psumsq[2048] | pcnt[2048] | scale[64] | shift[64]
// ---------------------------------------------------------------------------
__global__ __launch_bounds__(256) void mbn_stats(const float* __restrict__ x,
                                                 const float* __restrict__ mask,
                                                 float* __restrict__ ws) {
    const int blk  = blockIdx.x;        // 0..2047
    const int bc   = blk >> 1;
    const int half = blk & 1;
    const int b    = bc >> 6;
    const float* xp = x + (size_t)bc * HW + (size_t)half * HHW;
    const float* mp = mask + (size_t)b * HW + (size_t)half * HHW;

    float s = 0.f, ss = 0.f, cn = 0.f;
    #pragma unroll 4
    for (int i = threadIdx.x * 4; i < HHW; i += 256 * 4) {
        f4 xv = *reinterpret_cast<const f4*>(xp + i);
        f4 mv = *reinterpret_cast<const f4*>(mp + i);
        float v0 = mv.x > 0.5f ? 1.f : 0.f;
        float v1 = mv.y > 0.5f ? 1.f : 0.f;
        float v2 = mv.z > 0.5f ? 1.f : 0.f;
        float v3 = mv.w > 0.5f ? 1.f : 0.f;
        s  += xv.x * v0 + xv.y * v1 + xv.z * v2 + xv.w * v3;
        ss += xv.x * xv.x * v0 + xv.y * xv.y * v1
            + xv.z * xv.z * v2 + xv.w * xv.w * v3;
        cn += v0 + v1 + v2 + v3;
    }

    for (int off = 32; off > 0; off >>= 1) {
        s  += __shfl_down(s,  off);
        ss += __shfl_down(ss, off);
        cn += __shfl_down(cn, off);
    }
    __shared__ float red[3][4];
    const int wave = threadIdx.x >> 6;
    const int lane = threadIdx.x & 63;
    if (lane == 0) { red[0][wave] = s; red[1][wave] = ss; red[2][wave] = cn; }
    __syncthreads();
    if (threadIdx.x == 0) {
        s  = red[0][0] + red[0][1] + red[0][2] + red[0][3];
        ss = red[1][0] + red[1][1] + red[1][2] + red[1][3];
        cn = red[2][0] + red[2][1] + red[2][2] + red[2][3];
        ws[blk]        = s;
        ws[2048 + blk] = ss;
        ws[4096 + blk] = cn;
    }
}

// ---------------------------------------------------------------------------
// Kernel 2: fold stats -> per-channel scale/shift. Reference edge semantics:
// mean=0 if cnt==0, var=1 if cnt<=1.
// ---------------------------------------------------------------------------
__global__ __launch_bounds__(64) void mbn_finalize(const float* __restrict__ ws_in,
                                                   const float* __restrict__ weight,
                                                   const float* __restrict__ bias,
                                                   float* __restrict__ sc_sh) {
    const int c = threadIdx.x;          // 0..63
    float fm = 0.f, fv = 0.f;
    for (int b = 0; b < NB; ++b) {
        const int i0 = (b * NC + c) * 2;
        const float s  = ws_in[i0] + ws_in[i0 + 1];
        const float ss = ws_in[2048 + i0] + ws_in[2048 + i0 + 1];
        const float cn = ws_in[4096 + i0] + ws_in[4096 + i0 + 1];
        const float safe = fmaxf(cn, 1.f);
        const float mean = (cn > 0.f) ? (s / safe) : 0.f;
        const float sq   = ss - 2.f * mean * s + mean * mean * cn;
        const float var  = (cn > 1.f) ? (sq / safe) : 1.f;
        fm += mean;
        fv += var;
    }
    fm *= (1.f / NB);
    fv *= (1.f / NB);
    const float inv   = 1.f / sqrtf(fv + BN_EPS);
    const float scale = weight[c] * inv;
    const float shift = bias[c] - fm * scale;
    sc_sh[c]      = scale;
    sc_sh[64 + c] = shift;
}

// ---------------------------------------------------------------------------
// Kernel 3: elementwise apply: out = valid ? x*scale[c]+shift[c] : x
// float4 grid-stride; NONTEMPORAL stores so the 256 MiB `out` stream does
// not evict the L3-resident x (x == 256 MiB == full Infinity Cache).
// ---------------------------------------------------------------------------
__global__ __launch_bounds__(256) void mbn_apply(const float* __restrict__ x,
                                                 const float* __restrict__ mask,
                                                 const float* __restrict__ sc_sh,
                                                 float* __restrict__ out) {
    const size_t total4 = (size_t)NB * NC * HW / 4;   // 4,194,304
    const size_t stride = (size_t)gridDim.x * blockDim.x;
    for (size_t i = (size_t)blockIdx.x * blockDim.x + threadIdx.x;
         i < total4; i += stride) {
        const size_t e  = i * 4;
        const int    c  = (int)((e >> 16) & 63);
        const size_t b  = e >> 22;
        const size_t hw = e & 65535;
        f4 xv = *reinterpret_cast<const f4*>(x + e);
        f4 mv = *reinterpret_cast<const f4*>(mask + b * HW + hw);
        const float sc = sc_sh[c];
        const float sh = sc_sh[64 + c];
        f4 o;
        o.x = mv.x > 0.5f ? fmaf(xv.x, sc, sh) : xv.x;
        o.y = mv.y > 0.5f ? fmaf(xv.y, sc, sh) : xv.y;
        o.z = mv.z > 0.5f ? fmaf(xv.z, sc, sh) : xv.z;
        o.w = mv.w > 0.5f ? fmaf(xv.w, sc, sh) : xv.w;
        __builtin_nontemporal_store(o, reinterpret_cast<f4*>(out + e));
    }
}

extern "C" void kernel_launch(void* const* d_in, const int* in_sizes, int n_in,
                              void* d_out, int out_size, void* d_ws, size_t ws_size,
                              hipStream_t stream) {
    const float* x      = (const float*)d_in[0];
    const float* mask   = (const float*)d_in[1];
    const float* weight = (const float*)d_in[2];
    const float* bias   = (const float*)d_in[3];
    float* out   = (float*)d_out;
    float* ws    = (float*)d_ws;      // psum[2048] psumsq[2048] pcnt[2048]
    float* sc_sh = ws + 6144;         // scale[64] shift[64]

    mbn_stats<<<2048, 256, 0, stream>>>(x, mask, ws);
    mbn_finalize<<<1, 64, 0, stream>>>(ws, weight, bias, sc_sh);
    mbn_apply<<<4096, 256, 0, stream>>>(x, mask, sc_sh, out);
}

// Round 3
// 141.886 us; speedup vs baseline: 1.2662x; 1.0085x over previous
//
#include <hip/hip_runtime.h>

// Problem constants (from reference setup_inputs): B=16, C=64, H=W=256.
#define NB 16
#define NC 64
#define HW 65536            // 256*256
#define HHW 32768           // HW/2
#define BN_EPS 1e-5f

typedef float f4 __attribute__((ext_vector_type(4)));

// ---------------------------------------------------------------------------
// Kernel 1: per-(b,c,half) masked reduction. 2048 blocks x 256 threads.
// Streams x FORWARD -> at completion the MALL holds the tail of x.
// ws layout: psum[2048] | psumsq[2048] | pcnt[2048] | scale[64] | shift[64]
// ---------------------------------------------------------------------------
__global__ __launch_bounds__(256) void mbn_stats(const float* __restrict__ x,
                                                 const float* __restrict__ mask,
                                                 float* __restrict__ ws) {
    const int blk  = blockIdx.x;        // 0..2047
    const int bc   = blk >> 1;
    const int half = blk & 1;
    const int b    = bc >> 6;
    const float* xp = x + (size_t)bc * HW + (size_t)half * HHW;
    const float* mp = mask + (size_t)b * HW + (size_t)half * HHW;

    float s = 0.f, ss = 0.f, cn = 0.f;
    #pragma unroll 4
    for (int i = threadIdx.x * 4; i < HHW; i += 256 * 4) {
        f4 xv = *reinterpret_cast<const f4*>(xp + i);
        f4 mv = *reinterpret_cast<const f4*>(mp + i);
        float v0 = mv.x > 0.5f ? 1.f : 0.f;
        float v1 = mv.y > 0.5f ? 1.f : 0.f;
        float v2 = mv.z > 0.5f ? 1.f : 0.f;
        float v3 = mv.w > 0.5f ? 1.f : 0.f;
        s  += xv.x * v0 + xv.y * v1 + xv.z * v2 + xv.w * v3;
        ss += xv.x * xv.x * v0 + xv.y * xv.y * v1
            + xv.z * xv.z * v2 + xv.w * xv.w * v3;
        cn += v0 + v1 + v2 + v3;
    }

    for (int off = 32; off > 0; off >>= 1) {
        s  += __shfl_down(s,  off);
        ss += __shfl_down(ss, off);
        cn += __shfl_down(cn, off);
    }
    __shared__ float red[3][4];
    const int wave = threadIdx.x >> 6;
    const int lane = threadIdx.x & 63;
    if (lane == 0) { red[0][wave] = s; red[1][wave] = ss; red[2][wave] = cn; }
    __syncthreads();
    if (threadIdx.x == 0) {
        s  = red[0][0] + red[0][1] + red[0][2] + red[0][3];
        ss = red[1][0] + red[1][1] + red[1][2] + red[1][3];
        cn = red[2][0] + red[2][1] + red[2][2] + red[2][3];
        ws[blk]        = s;
        ws[2048 + blk] = ss;
        ws[4096 + blk] = cn;
    }
}

// ---------------------------------------------------------------------------
// Kernel 2: fold stats -> per-channel scale/shift. Reference edge semantics:
// mean=0 if cnt==0, var=1 if cnt<=1.
// ---------------------------------------------------------------------------
__global__ __launch_bounds__(64) void mbn_finalize(const float* __restrict__ ws_in,
                                                   const float* __restrict__ weight,
                                                   const float* __restrict__ bias,
                                                   float* __restrict__ sc_sh) {
    const int c = threadIdx.x;          // 0..63
    float fm = 0.f, fv = 0.f;
    for (int b = 0; b < NB; ++b) {
        const int i0 = (b * NC + c) * 2;
        const float s  = ws_in[i0] + ws_in[i0 + 1];
        const float ss = ws_in[2048 + i0] + ws_in[2048 + i0 + 1];
        const float cn = ws_in[4096 + i0] + ws_in[4096 + i0 + 1];
        const float safe = fmaxf(cn, 1.f);
        const float mean = (cn > 0.f) ? (s / safe) : 0.f;
        const float sq   = ss - 2.f * mean * s + mean * mean * cn;
        const float var  = (cn > 1.f) ? (sq / safe) : 1.f;
        fm += mean;
        fv += var;
    }
    fm *= (1.f / NB);
    fv *= (1.f / NB);
    const float inv   = 1.f / sqrtf(fv + BN_EPS);
    const float scale = weight[c] * inv;
    const float shift = bias[c] - fm * scale;
    sc_sh[c]      = scale;
    sc_sh[64 + c] = shift;
}

// ---------------------------------------------------------------------------
// Kernel 3: elementwise apply, REVERSED traversal (boustrophedon).
// Stats left the tail of x in the MALL; block 0 (dispatched first) starts
// at the tail and walks backward -> x reads become Infinity-Cache hits.
// Per-wave address sets stay contiguous (coalescing unaffected).
// Nontemporal stores keep `out` from evicting x.
// ---------------------------------------------------------------------------
__global__ __launch_bounds__(256) void mbn_apply(const float* __restrict__ x,
                                                 const float* __restrict__ mask,
                                                 const float* __restrict__ sc_sh,
                                                 float* __restrict__ out) {
    const size_t total4 = (size_t)NB * NC * HW / 4;   // 16,777,216 float4s
    const size_t stride = (size_t)gridDim.x * blockDim.x;
    for (size_t i = (size_t)blockIdx.x * blockDim.x + threadIdx.x;
         i < total4; i += stride) {
        const size_t j  = total4 - 1 - i;             // reversed order
        const size_t e  = j * 4;
        const int    c  = (int)((e >> 16) & 63);
        const size_t b  = e >> 22;
        const size_t hw = e & 65535;
        f4 xv = *reinterpret_cast<const f4*>(x + e);
        f4 mv = *reinterpret_cast<const f4*>(mask + b * HW + hw);
        const float sc = sc_sh[c];
        const float sh = sc_sh[64 + c];
        f4 o;
        o.x = mv.x > 0.5f ? fmaf(xv.x, sc, sh) : xv.x;
        o.y = mv.y > 0.5f ? fmaf(xv.y, sc, sh) : xv.y;
        o.z = mv.z > 0.5f ? fmaf(xv.z, sc, sh) : xv.z;
        o.w = mv.w > 0.5f ? fmaf(xv.w, sc, sh) : xv.w;
        __builtin_nontemporal_store(o, reinterpret_cast<f4*>(out + e));
    }
}

extern "C" void kernel_launch(void* const* d_in, const int* in_sizes, int n_in,
                              void* d_out, int out_size, void* d_ws, size_t ws_size,
                              hipStream_t stream) {
    const float* x      = (const float*)d_in[0];
    const float* mask   = (const float*)d_in[1];
    const float* weight = (const float*)d_in[2];
    const float* bias   = (const float*)d_in[3];
    float* out   = (float*)d_out;
    float* ws    = (float*)d_ws;      // psum[2048] psumsq[2048] pcnt[2048]
    float* sc_sh = ws + 6144;         // scale[64] shift[64]

    mbn_stats<<<2048, 256, 0, stream>>>(x, mask, ws);
    mbn_finalize<<<1, 64, 0, stream>>>(ws, weight, bias, sc_sh);
    mbn_apply<<<4096, 256, 0, stream>>>(x, mask, sc_sh, out);
}